// Round 1
// baseline (119.618 us; speedup 1.0000x reference)
//
#include <hip/hip_runtime.h>
#include <hip/hip_bf16.h>

// Shapes
#define BB 16
#define PP 64
#define NN 4096
#define DD 768

typedef __attribute__((ext_vector_type(4))) float f32x4;
typedef __attribute__((ext_vector_type(8))) __bf16 bf16x8;
typedef __attribute__((ext_vector_type(4))) __bf16 bf16x4;

__device__ __forceinline__ f32x4 mfma16(bf16x8 a, bf16x8 b, f32x4 c) {
    return __builtin_amdgcn_mfma_f32_16x16x32_bf16(a, b, c, 0, 0, 0);
}

// ---------------------------------------------------------------------------
// K1: S[b,p,n] = scale * sum_d q[b,p,d] * x[b,n,d]
// grid: 256 = 16 batches x 16 chunks of 256 tokens. block: 256 (4 waves).
// wave w computes [64 p x 64 n] slice; LDS-staged bf16 tiles over d in steps of 64.
// ---------------------------------------------------------------------------
__global__ __launch_bounds__(256) void k_scores(const float* __restrict__ x,
                                                const float* __restrict__ q,
                                                float* __restrict__ S) {
    const int b  = blockIdx.x >> 4;
    const int n0 = (blockIdx.x & 15) * 256;
    __shared__ __bf16 lq[64][72];    // stride 72 elems = 144 B (16B-aligned rows, 2-way banks)
    __shared__ __bf16 lk[256][72];

    const int t = threadIdx.x;
    const int lane = t & 63, w = t >> 6;
    const int i  = t & 15;    // float4 column index within 64-wide d-tile
    const int r0 = t >> 4;

    f32x4 acc[4][4] = {};

    for (int kd = 0; kd < DD; kd += 64) {
        __syncthreads();
        // stage Q tile: 64 x 64
        #pragma unroll
        for (int pass = 0; pass < 4; ++pass) {
            const int r = r0 + pass * 16;
            const float4 v = *(const float4*)&q[((size_t)b * PP + r) * DD + kd + i * 4];
            bf16x4 h = {(__bf16)v.x, (__bf16)v.y, (__bf16)v.z, (__bf16)v.w};
            *(bf16x4*)&lq[r][i * 4] = h;
        }
        // stage K tile: 256 x 64
        #pragma unroll
        for (int pass = 0; pass < 16; ++pass) {
            const int r = r0 + pass * 16;
            const float4 v = *(const float4*)&x[((size_t)b * NN + n0 + r) * DD + kd + i * 4];
            bf16x4 h = {(__bf16)v.x, (__bf16)v.y, (__bf16)v.z, (__bf16)v.w};
            *(bf16x4*)&lk[r][i * 4] = h;
        }
        __syncthreads();

        const int row = lane & 15, hi = lane >> 4;
        #pragma unroll
        for (int ks = 0; ks < 2; ++ks) {
            bf16x8 af[4], bfr[4];
            #pragma unroll
            for (int am = 0; am < 4; ++am)
                af[am] = *(bf16x8*)&lq[am * 16 + row][ks * 32 + hi * 8];
            #pragma unroll
            for (int an = 0; an < 4; ++an)
                bfr[an] = *(bf16x8*)&lk[w * 64 + an * 16 + row][ks * 32 + hi * 8];
            #pragma unroll
            for (int am = 0; am < 4; ++am)
                #pragma unroll
                for (int an = 0; an < 4; ++an)
                    acc[am][an] = mfma16(af[am], bfr[an], acc[am][an]);
        }
    }

    const float scale = 0.036084391824351615f;  // 768^-0.5
    const int row = lane & 15, hi = lane >> 4;
    #pragma unroll
    for (int am = 0; am < 4; ++am)
        #pragma unroll
        for (int an = 0; an < 4; ++an)
            #pragma unroll
            for (int j = 0; j < 4; ++j) {
                const int p = am * 16 + hi * 4 + j;
                const int n = n0 + w * 64 + an * 16 + row;
                S[((size_t)b * PP + p) * NN + n] = acc[am][an][j] * scale;
            }
}

// ---------------------------------------------------------------------------
// K2: per-row softmax, normalized P written as bf16. grid: 1024 rows.
// ---------------------------------------------------------------------------
__global__ __launch_bounds__(256) void k_softmax(const float* __restrict__ S,
                                                 __bf16* __restrict__ Pm) {
    const int rowi = blockIdx.x;
    const float* s = S + (size_t)rowi * NN;
    __bf16* pr = Pm + (size_t)rowi * NN;
    const int t = threadIdx.x;
    const int w = t >> 6, lane = t & 63;

    float v[16];
    float m = -1e30f;
    #pragma unroll
    for (int i = 0; i < 4; ++i) {
        const float4 f = *(const float4*)&s[(i * 256 + t) * 4];
        v[i*4+0] = f.x; v[i*4+1] = f.y; v[i*4+2] = f.z; v[i*4+3] = f.w;
        m = fmaxf(m, fmaxf(fmaxf(f.x, f.y), fmaxf(f.z, f.w)));
    }
    #pragma unroll
    for (int o = 32; o > 0; o >>= 1) m = fmaxf(m, __shfl_xor(m, o));
    __shared__ float redm[4], redl[4];
    if (lane == 0) redm[w] = m;
    __syncthreads();
    m = fmaxf(fmaxf(redm[0], redm[1]), fmaxf(redm[2], redm[3]));

    float l = 0.f;
    #pragma unroll
    for (int ii = 0; ii < 16; ++ii) { v[ii] = __expf(v[ii] - m); l += v[ii]; }
    #pragma unroll
    for (int o = 32; o > 0; o >>= 1) l += __shfl_xor(l, o);
    if (lane == 0) redl[w] = l;
    __syncthreads();
    l = redl[0] + redl[1] + redl[2] + redl[3];
    const float linv = 1.f / l;

    #pragma unroll
    for (int i = 0; i < 4; ++i) {
        bf16x4 h = {(__bf16)(v[i*4+0] * linv), (__bf16)(v[i*4+1] * linv),
                    (__bf16)(v[i*4+2] * linv), (__bf16)(v[i*4+3] * linv)};
        *(bf16x4*)&pr[(i * 256 + t) * 4] = h;
    }
}

// ---------------------------------------------------------------------------
// K3: out[b,p,d] = sum_n P[b,p,n] * x[b,n,d]
// grid: 192 = 16 batches x 12 d-tiles of 64. block: 256 (4 waves).
// wave w computes [64 p x 16 d]; V staged TRANSPOSED in LDS ([d][n]) so the
// B-fragment (k = n contiguous per lane) is a single ds_read_b128.
// ---------------------------------------------------------------------------
__global__ __launch_bounds__(256) void k_pv(const float* __restrict__ x,
                                            const __bf16* __restrict__ Pm,
                                            float* __restrict__ out) {
    const int b  = blockIdx.x / 12;
    const int d0 = (blockIdx.x % 12) * 64;
    __shared__ __bf16 lp[64][72];   // P tile [p][n]
    __shared__ __bf16 lv[64][72];   // V tile transposed [d][n]

    const int t = threadIdx.x;
    const int lane = t & 63, w = t >> 6;
    f32x4 acc[4] = {};

    for (int n0 = 0; n0 < NN; n0 += 64) {
        __syncthreads();
        // stage P tile: 64 p x 64 n (bf16 source, direct copy)
        {
            const int r = t >> 2;
            #pragma unroll
            for (int pass = 0; pass < 2; ++pass) {
                const int ii = (t & 3) + pass * 4;
                *(bf16x8*)&lp[r][ii * 8] =
                    *(const bf16x8*)&Pm[((size_t)b * PP + r) * NN + n0 + ii * 8];
            }
        }
        // stage V tile transposed: lv[dd][nn] = x[b][n0+nn][d0+dd]
        {
            const int ii = t & 15;   // d float4 index
            const int r0 = t >> 4;
            #pragma unroll
            for (int pass = 0; pass < 4; ++pass) {
                const int nn = r0 + pass * 16;
                const float4 v = *(const float4*)&x[((size_t)b * NN + n0 + nn) * DD + d0 + ii * 4];
                lv[ii * 4 + 0][nn] = (__bf16)v.x;
                lv[ii * 4 + 1][nn] = (__bf16)v.y;
                lv[ii * 4 + 2][nn] = (__bf16)v.z;
                lv[ii * 4 + 3][nn] = (__bf16)v.w;
            }
        }
        __syncthreads();

        const int row = lane & 15, hi = lane >> 4;
        #pragma unroll
        for (int ks = 0; ks < 2; ++ks) {
            const bf16x8 bfrag = *(bf16x8*)&lv[w * 16 + row][ks * 32 + hi * 8];
            #pragma unroll
            for (int am = 0; am < 4; ++am) {
                const bf16x8 afrag = *(bf16x8*)&lp[am * 16 + row][ks * 32 + hi * 8];
                acc[am] = mfma16(afrag, bfrag, acc[am]);
            }
        }
    }

    const int col = lane & 15, hi = lane >> 4;
    #pragma unroll
    for (int am = 0; am < 4; ++am)
        #pragma unroll
        for (int j = 0; j < 4; ++j) {
            const int p = am * 16 + hi * 4 + j;
            out[((size_t)b * PP + p) * DD + d0 + w * 16 + col] = acc[am][j];
        }
}

extern "C" void kernel_launch(void* const* d_in, const int* in_sizes, int n_in,
                              void* d_out, int out_size, void* d_ws, size_t ws_size,
                              hipStream_t stream) {
    const float* x = (const float*)d_in[0];   // [16, 4096, 768]
    const float* q = (const float*)d_in[1];   // [16, 64, 768]
    float* out = (float*)d_out;               // [16, 64, 768]

    float* S = (float*)d_ws;                                        // 16 MB
    __bf16* Pm = (__bf16*)((char*)d_ws + (size_t)BB * PP * NN * 4); // 8 MB

    hipLaunchKernelGGL(k_scores,  dim3(BB * 16), dim3(256), 0, stream, x, q, S);
    hipLaunchKernelGGL(k_softmax, dim3(BB * PP), dim3(256), 0, stream, S, Pm);
    hipLaunchKernelGGL(k_pv,      dim3(BB * 12), dim3(256), 0, stream, x, Pm, out);
}

// Round 2
// 112.306 us; speedup vs baseline: 1.0651x; 1.0651x over previous
//
#include <hip/hip_runtime.h>
#include <hip/hip_bf16.h>

// Shapes
#define BB 16
#define PP 64
#define NN 4096
#define DD 768

typedef __attribute__((ext_vector_type(4))) float f32x4;
typedef __attribute__((ext_vector_type(8))) __bf16 bf16x8;
typedef __attribute__((ext_vector_type(4))) __bf16 bf16x4;
typedef __attribute__((ext_vector_type(2))) __bf16 bf16x2;

__device__ __forceinline__ f32x4 mfma16(bf16x8 a, bf16x8 b, f32x4 c) {
    return __builtin_amdgcn_mfma_f32_16x16x32_bf16(a, b, c, 0, 0, 0);
}

// ---------------------------------------------------------------------------
// K1: S[b,p,n] = scale * sum_d q[b,p,d] * x[b,n,d]
// grid: 512 = 16 b x 32 chunks of 128 tokens -> 2 wgs/CU (latency overlap).
// block 256 (4 waves); wave w computes [64 p x 32 n]; d-tiles of 64.
// ---------------------------------------------------------------------------
__global__ __launch_bounds__(256) void k_scores(const float* __restrict__ x,
                                                const float* __restrict__ q,
                                                float* __restrict__ S) {
    const int b  = blockIdx.x >> 5;
    const int n0 = (blockIdx.x & 31) * 128;
    __shared__ __bf16 lq[64][72];    // stride 72 elems = 144 B (16B-aligned rows)
    __shared__ __bf16 lk[128][72];

    const int t = threadIdx.x;
    const int lane = t & 63, w = t >> 6;
    const int i  = t & 15;    // float4 column index within 64-wide d-tile
    const int r0 = t >> 4;

    f32x4 acc[4][2] = {};

    for (int kd = 0; kd < DD; kd += 64) {
        __syncthreads();
        // stage Q tile: 64 x 64
        #pragma unroll
        for (int pass = 0; pass < 4; ++pass) {
            const int r = r0 + pass * 16;
            const float4 v = *(const float4*)&q[((size_t)b * PP + r) * DD + kd + i * 4];
            bf16x4 h = {(__bf16)v.x, (__bf16)v.y, (__bf16)v.z, (__bf16)v.w};
            *(bf16x4*)&lq[r][i * 4] = h;
        }
        // stage K tile: 128 x 64
        #pragma unroll
        for (int pass = 0; pass < 8; ++pass) {
            const int r = r0 + pass * 16;
            const float4 v = *(const float4*)&x[((size_t)b * NN + n0 + r) * DD + kd + i * 4];
            bf16x4 h = {(__bf16)v.x, (__bf16)v.y, (__bf16)v.z, (__bf16)v.w};
            *(bf16x4*)&lk[r][i * 4] = h;
        }
        __syncthreads();

        const int row = lane & 15, hi = lane >> 4;
        #pragma unroll
        for (int ks = 0; ks < 2; ++ks) {
            bf16x8 af[4], bfr[2];
            #pragma unroll
            for (int am = 0; am < 4; ++am)
                af[am] = *(bf16x8*)&lq[am * 16 + row][ks * 32 + hi * 8];
            #pragma unroll
            for (int an = 0; an < 2; ++an)
                bfr[an] = *(bf16x8*)&lk[w * 32 + an * 16 + row][ks * 32 + hi * 8];
            #pragma unroll
            for (int am = 0; am < 4; ++am)
                #pragma unroll
                for (int an = 0; an < 2; ++an)
                    acc[am][an] = mfma16(af[am], bfr[an], acc[am][an]);
        }
    }

    const float scale = 0.036084391824351615f;  // 768^-0.5
    const int row = lane & 15, hi = lane >> 4;
    #pragma unroll
    for (int am = 0; am < 4; ++am)
        #pragma unroll
        for (int an = 0; an < 2; ++an)
            #pragma unroll
            for (int j = 0; j < 4; ++j) {
                const int p = am * 16 + hi * 4 + j;
                const int n = n0 + w * 32 + an * 16 + row;
                S[((size_t)b * PP + p) * NN + n] = acc[am][an][j] * scale;
            }
}

// ---------------------------------------------------------------------------
// K2: per-row softmax, normalized P written as bf16. grid: 1024 rows.
// ---------------------------------------------------------------------------
__global__ __launch_bounds__(256) void k_softmax(const float* __restrict__ S,
                                                 __bf16* __restrict__ Pm) {
    const int rowi = blockIdx.x;
    const float* s = S + (size_t)rowi * NN;
    __bf16* pr = Pm + (size_t)rowi * NN;
    const int t = threadIdx.x;
    const int w = t >> 6, lane = t & 63;

    float v[16];
    float m = -1e30f;
    #pragma unroll
    for (int i = 0; i < 4; ++i) {
        const float4 f = *(const float4*)&s[(i * 256 + t) * 4];
        v[i*4+0] = f.x; v[i*4+1] = f.y; v[i*4+2] = f.z; v[i*4+3] = f.w;
        m = fmaxf(m, fmaxf(fmaxf(f.x, f.y), fmaxf(f.z, f.w)));
    }
    #pragma unroll
    for (int o = 32; o > 0; o >>= 1) m = fmaxf(m, __shfl_xor(m, o));
    __shared__ float redm[4], redl[4];
    if (lane == 0) redm[w] = m;
    __syncthreads();
    m = fmaxf(fmaxf(redm[0], redm[1]), fmaxf(redm[2], redm[3]));

    float l = 0.f;
    #pragma unroll
    for (int ii = 0; ii < 16; ++ii) { v[ii] = __expf(v[ii] - m); l += v[ii]; }
    #pragma unroll
    for (int o = 32; o > 0; o >>= 1) l += __shfl_xor(l, o);
    if (lane == 0) redl[w] = l;
    __syncthreads();
    l = redl[0] + redl[1] + redl[2] + redl[3];
    const float linv = 1.f / l;

    #pragma unroll
    for (int i = 0; i < 4; ++i) {
        bf16x4 h = {(__bf16)(v[i*4+0] * linv), (__bf16)(v[i*4+1] * linv),
                    (__bf16)(v[i*4+2] * linv), (__bf16)(v[i*4+3] * linv)};
        *(bf16x4*)&pr[(i * 256 + t) * 4] = h;
    }
}

// ---------------------------------------------------------------------------
// K3: partial[sp][b,p,d] = sum_{n in split sp} P[b,p,n] * x[b,n,d]
// grid: 768 = 16 b x 12 d-tiles x 4 n-splits -> 3 wgs/CU.
// V staged transposed [d][n] with XOR swizzle col = n ^ (((d>>2)&7)<<3):
//   b32 writes land at the 2/bank minimum; b128 reads peak at the 8/bank
//   b128 structural minimum (bank arithmetic in journal).
// ---------------------------------------------------------------------------
__global__ __launch_bounds__(256) void k_pv(const float* __restrict__ x,
                                            const __bf16* __restrict__ Pm,
                                            float* __restrict__ part) {
    const int b   = blockIdx.x / 48;
    const int rem = blockIdx.x % 48;
    const int d0  = (rem % 12) * 64;
    const int sp  = rem / 12;
    const int nbase = sp * (NN / 4);

    __shared__ __bf16 lp[64][72];   // P tile [p][n]
    __shared__ __bf16 lv[64][72];   // V tile transposed [d][n], XOR-swizzled cols

    const int t = threadIdx.x;
    const int lane = t & 63, w = t >> 6;
    f32x4 acc[4] = {};

    for (int it = 0; it < NN / 4; it += 64) {
        const int n0 = nbase + it;
        __syncthreads();
        // stage P tile: 64 p x 64 n (bf16 source, direct b128 copy)
        {
            const int r = t >> 2;
            #pragma unroll
            for (int pass = 0; pass < 2; ++pass) {
                const int ii = (t & 3) + pass * 4;
                *(bf16x8*)&lp[r][ii * 8] =
                    *(const bf16x8*)&Pm[((size_t)b * PP + r) * NN + n0 + ii * 8];
            }
        }
        // stage V tile transposed+swizzled: lv[d][n ^ key] = x[b][n0+n][d0+d]
        {
            const int ii = t & 15;   // d float4 index
            const int rr = t >> 4;   // n-pair index within 32-n half
            #pragma unroll
            for (int pass = 0; pass < 2; ++pass) {
                const int n = pass * 32 + rr * 2;
                const float4 va = *(const float4*)&x[((size_t)b * NN + n0 + n) * DD + d0 + ii * 4];
                const float4 vb = *(const float4*)&x[((size_t)b * NN + n0 + n + 1) * DD + d0 + ii * 4];
                const int col = n ^ ((ii & 7) << 3);
                const float a0[4] = {va.x, va.y, va.z, va.w};
                const float b0[4] = {vb.x, vb.y, vb.z, vb.w};
                #pragma unroll
                for (int c = 0; c < 4; ++c) {
                    bf16x2 h = {(__bf16)a0[c], (__bf16)b0[c]};
                    *(bf16x2*)&lv[ii * 4 + c][col] = h;
                }
            }
        }
        __syncthreads();

        const int row = lane & 15, hi = lane >> 4;
        const int key = (4 * w + (row >> 2)) & 7;
        #pragma unroll
        for (int ks = 0; ks < 2; ++ks) {
            const int col = (ks * 32 + hi * 8) ^ (key << 3);
            const bf16x8 bfrag = *(bf16x8*)&lv[w * 16 + row][col];
            #pragma unroll
            for (int am = 0; am < 4; ++am) {
                const bf16x8 afrag = *(bf16x8*)&lp[am * 16 + row][ks * 32 + hi * 8];
                acc[am] = mfma16(afrag, bfrag, acc[am]);
            }
        }
    }

    const int col = lane & 15, hi = lane >> 4;
    #pragma unroll
    for (int am = 0; am < 4; ++am)
        #pragma unroll
        for (int j = 0; j < 4; ++j) {
            const int p = am * 16 + hi * 4 + j;
            part[(size_t)sp * (BB * PP * DD) + ((size_t)b * PP + p) * DD + d0 + w * 16 + col] = acc[am][j];
        }
}

// ---------------------------------------------------------------------------
// K4: out = sum over 4 n-split partials. grid: 768 x 256 x f32x4.
// ---------------------------------------------------------------------------
__global__ __launch_bounds__(256) void k_reduce(const float* __restrict__ part,
                                                float* __restrict__ out) {
    const size_t idx = ((size_t)blockIdx.x * 256 + threadIdx.x);
    const f32x4* p4 = (const f32x4*)part;
    const size_t stride4 = (size_t)BB * PP * DD / 4;
    f32x4 v = p4[idx] + p4[stride4 + idx] + p4[2 * stride4 + idx] + p4[3 * stride4 + idx];
    ((f32x4*)out)[idx] = v;
}

extern "C" void kernel_launch(void* const* d_in, const int* in_sizes, int n_in,
                              void* d_out, int out_size, void* d_ws, size_t ws_size,
                              hipStream_t stream) {
    const float* x = (const float*)d_in[0];   // [16, 4096, 768]
    const float* q = (const float*)d_in[1];   // [16, 64, 768]
    float* out = (float*)d_out;               // [16, 64, 768]

    float* S = (float*)d_ws;                                        // 16.8 MB
    __bf16* Pm = (__bf16*)((char*)d_ws + (size_t)BB * PP * NN * 4); // 8.4 MB
    float* part = S;  // partials (12.6 MB) reuse S region after k_softmax consumed it

    hipLaunchKernelGGL(k_scores,  dim3(BB * 32), dim3(256), 0, stream, x, q, S);
    hipLaunchKernelGGL(k_softmax, dim3(BB * PP), dim3(256), 0, stream, S, Pm);
    hipLaunchKernelGGL(k_pv,      dim3(768),     dim3(256), 0, stream, x, Pm, part);
    hipLaunchKernelGGL(k_reduce,  dim3(768),     dim3(256), 0, stream, part, out);
}

// Round 3
// 105.871 us; speedup vs baseline: 1.1298x; 1.0608x over previous
//
#include <hip/hip_runtime.h>
#include <hip/hip_bf16.h>

// Shapes
#define BB 16
#define PP 64
#define NN 4096
#define DD 768

typedef __attribute__((ext_vector_type(4))) float f32x4;
typedef __attribute__((ext_vector_type(8))) __bf16 bf16x8;
typedef __attribute__((ext_vector_type(4))) __bf16 bf16x4;
typedef __attribute__((ext_vector_type(2))) __bf16 bf16x2;

__device__ __forceinline__ f32x4 mfma16(bf16x8 a, bf16x8 b, f32x4 c) {
    return __builtin_amdgcn_mfma_f32_16x16x32_bf16(a, b, c, 0, 0, 0);
}

// XOR swizzle key for k_qk_sm LDS tiles: spreads rows r, r+8, r+16, r+24 that
// would otherwise alias to the same bank-quad on b128 frag reads.
__device__ __forceinline__ int SW(int r) { return ((r >> 3) & 3) << 3; }

// ---------------------------------------------------------------------------
// K1: fused QK^T + local softmax over a 256-token chunk.
//   P[b,p,n] = exp(scale*S - m_chunk)  (bf16, unnormalized)
//   statm/statl[(b*16+chunk)*64+p] = m_chunk, l_chunk
// grid 256 = 16 b x 16 chunks (1 block/CU, no tail). block 512 (8 waves).
// wave w computes S slice [64 p x 32 n]. Staging: batched reg loads -> bf16
// LDS (swizzled). kd tiles of 64.
// ---------------------------------------------------------------------------
__global__ __launch_bounds__(512) void k_qk_sm(const float* __restrict__ x,
                                               const float* __restrict__ q,
                                               __bf16* __restrict__ Pm,
                                               float* __restrict__ statm,
                                               float* __restrict__ statl) {
    const int b  = blockIdx.x >> 4;
    const int sp = blockIdx.x & 15;      // chunk id (256 tokens)
    const int n0 = sp * 256;

    __shared__ __bf16 lk[256][64];       // swizzled cols
    __shared__ __bf16 lq[64][64];        // swizzled cols
    __shared__ float  wred[8][64];
    __shared__ float  mfin[64];
    __bf16* PO = &lk[0][0];              // reused after last MFMA: P [64][256] linear

    const int t = threadIdx.x;
    const int w = t >> 6, lane = t & 63;
    const int l15 = lane & 15, hi = lane >> 4;

    const int rK = t >> 1, hK = t & 1;   // K-tile row / 32-float half
    const int rQ = (t & 127) >> 1, hQ = t & 1;

    f32x4 acc[4][2] = {};

    const size_t xrow = ((size_t)b * NN + n0 + rK) * DD + hK * 32;
    const size_t qrow = ((size_t)b * PP + rQ) * DD + hQ * 32;

    for (int kd = 0; kd < DD; kd += 64) {
        // ---- batched loads (issued before barrier; overlap prev MFMA) ----
        float4 tk[8], tq[8];
        #pragma unroll
        for (int i = 0; i < 8; ++i) tk[i] = *(const float4*)&x[xrow + kd + 4 * i];
        if (t < 128) {
            #pragma unroll
            for (int i = 0; i < 8; ++i) tq[i] = *(const float4*)&q[qrow + kd + 4 * i];
        }
        __syncthreads();   // prev iter's frag reads done
        // ---- convert + LDS write (swizzled) ----
        #pragma unroll
        for (int j = 0; j < 4; ++j) {
            const float4 a = tk[2 * j], c = tk[2 * j + 1];
            bf16x8 h = {(__bf16)a.x, (__bf16)a.y, (__bf16)a.z, (__bf16)a.w,
                        (__bf16)c.x, (__bf16)c.y, (__bf16)c.z, (__bf16)c.w};
            *(bf16x8*)&lk[rK][(hK * 32 + 8 * j) ^ SW(rK)] = h;
        }
        if (t < 128) {
            #pragma unroll
            for (int j = 0; j < 4; ++j) {
                const float4 a = tq[2 * j], c = tq[2 * j + 1];
                bf16x8 h = {(__bf16)a.x, (__bf16)a.y, (__bf16)a.z, (__bf16)a.w,
                            (__bf16)c.x, (__bf16)c.y, (__bf16)c.z, (__bf16)c.w};
                *(bf16x8*)&lq[rQ][(hQ * 32 + 8 * j) ^ SW(rQ)] = h;
            }
        }
        __syncthreads();
        // ---- MFMA ----
        #pragma unroll
        for (int ks = 0; ks < 2; ++ks) {
            bf16x8 af[4], bfr[2];
            #pragma unroll
            for (int am = 0; am < 4; ++am) {
                const int r = am * 16 + l15;
                af[am] = *(bf16x8*)&lq[r][(ks * 32 + hi * 8) ^ SW(r)];
            }
            #pragma unroll
            for (int an = 0; an < 2; ++an) {
                const int r = w * 32 + an * 16 + l15;
                bfr[an] = *(bf16x8*)&lk[r][(ks * 32 + hi * 8) ^ SW(r)];
            }
            #pragma unroll
            for (int am = 0; am < 4; ++am)
                #pragma unroll
                for (int an = 0; an < 2; ++an)
                    acc[am][an] = mfma16(af[am], bfr[an], acc[am][an]);
        }
    }

    // ---- local softmax over the 256-token chunk ----
    const float scale = 0.036084391824351615f;  // 768^-0.5
    float sv[4][2][4];
    #pragma unroll
    for (int am = 0; am < 4; ++am)
        #pragma unroll
        for (int an = 0; an < 2; ++an)
            #pragma unroll
            for (int j = 0; j < 4; ++j) sv[am][an][j] = acc[am][an][j] * scale;

    // per-row max within wave slice: reduce over l15 (16 lanes)
    float pm[4][4];
    #pragma unroll
    for (int am = 0; am < 4; ++am)
        #pragma unroll
        for (int j = 0; j < 4; ++j) pm[am][j] = fmaxf(sv[am][0][j], sv[am][1][j]);
    #pragma unroll
    for (int off = 1; off < 16; off <<= 1)
        #pragma unroll
        for (int am = 0; am < 4; ++am)
            #pragma unroll
            for (int j = 0; j < 4; ++j) pm[am][j] = fmaxf(pm[am][j], __shfl_xor(pm[am][j], off));
    if (l15 == 0)
        #pragma unroll
        for (int am = 0; am < 4; ++am)
            #pragma unroll
            for (int j = 0; j < 4; ++j) wred[w][am * 16 + hi * 4 + j] = pm[am][j];
    __syncthreads();
    if (t < 64) {
        float m = wred[0][t];
        #pragma unroll
        for (int ww = 1; ww < 8; ++ww) m = fmaxf(m, wred[ww][t]);
        mfin[t] = m;
    }
    __syncthreads();

    // exp, row-sum, write P (lk reused as [64][256] linear)
    float ls[4][4] = {};
    #pragma unroll
    for (int am = 0; am < 4; ++am)
        #pragma unroll
        for (int j = 0; j < 4; ++j) {
            const int p = am * 16 + hi * 4 + j;
            const float m = mfin[p];
            #pragma unroll
            for (int an = 0; an < 2; ++an) {
                const float e = __expf(sv[am][an][j] - m);
                ls[am][j] += e;
                PO[p * 256 + w * 32 + an * 16 + l15] = (__bf16)e;
            }
        }
    #pragma unroll
    for (int off = 1; off < 16; off <<= 1)
        #pragma unroll
        for (int am = 0; am < 4; ++am)
            #pragma unroll
            for (int j = 0; j < 4; ++j) ls[am][j] += __shfl_xor(ls[am][j], off);
    if (l15 == 0)
        #pragma unroll
        for (int am = 0; am < 4; ++am)
            #pragma unroll
            for (int j = 0; j < 4; ++j) wred[w][am * 16 + hi * 4 + j] = ls[am][j];
    __syncthreads();

    if (t < 64) {
        float l = 0.f;
        #pragma unroll
        for (int ww = 0; ww < 8; ++ww) l += wred[ww][t];
        const size_t si = ((size_t)b * 16 + sp) * 64 + t;
        statm[si] = mfin[t];
        statl[si] = l;
    }
    // copy P chunk to global (coalesced b128)
    #pragma unroll
    for (int rnd = 0; rnd < 4; ++rnd) {
        const int idx = rnd * 4096 + t * 8;     // elem index in [64][256]
        const int row = idx >> 8, col = idx & 255;
        *(bf16x8*)&Pm[((size_t)b * PP + row) * NN + n0 + col] = *(bf16x8*)&PO[idx];
    }
}

// ---------------------------------------------------------------------------
// K3: partial[sp][b,p,d] = sum_{c in split} exp(m_c - M) * sum_{n in c} P_c*V
// grid 768 = 16 b x 12 d-tiles x 4 n-splits (1024 tokens each). block 256.
// Chunk rescale folded into fp32 accumulators at 256-token boundaries.
// ---------------------------------------------------------------------------
__global__ __launch_bounds__(256) void k_pv(const float* __restrict__ x,
                                            const __bf16* __restrict__ Pm,
                                            const float* __restrict__ statm,
                                            float* __restrict__ part) {
    const int b   = blockIdx.x / 48;
    const int rem = blockIdx.x % 48;
    const int d0  = (rem % 12) * 64;
    const int sp  = rem / 12;
    const int nbase = sp * (NN / 4);

    __shared__ __bf16 lp[64][72];   // P tile [p][n]
    __shared__ __bf16 lv[64][72];   // V tile transposed [d][n], XOR-swizzled cols
    __shared__ float  rsc[4][64];   // exp(m_c - M) for this split's 4 chunks

    const int t = threadIdx.x;
    const int lane = t & 63, w = t >> 6;

    if (t < 64) {
        float M = -1e30f;
        #pragma unroll
        for (int c = 0; c < 16; ++c) M = fmaxf(M, statm[((size_t)b * 16 + c) * 64 + t]);
        #pragma unroll
        for (int cl = 0; cl < 4; ++cl)
            rsc[cl][t] = __expf(statm[((size_t)b * 16 + sp * 4 + cl) * 64 + t] - M);
    }

    f32x4 acc_tot[4] = {};
    f32x4 acc_in[4] = {};

    const int rP = t >> 2;
    const int iiV = t & 15, rrV = t >> 4;

    for (int it = 0; it < 16; ++it) {
        const int n0 = nbase + it * 64;
        // batched loads (before barrier)
        bf16x8 tp[2];
        #pragma unroll
        for (int pass = 0; pass < 2; ++pass) {
            const int ii = (t & 3) + pass * 4;
            tp[pass] = *(const bf16x8*)&Pm[((size_t)b * PP + rP) * NN + n0 + ii * 8];
        }
        float4 tv[4];
        #pragma unroll
        for (int pass = 0; pass < 2; ++pass) {
            const int n = pass * 32 + rrV * 2;
            tv[2*pass]   = *(const float4*)&x[((size_t)b * NN + n0 + n) * DD + d0 + iiV * 4];
            tv[2*pass+1] = *(const float4*)&x[((size_t)b * NN + n0 + n + 1) * DD + d0 + iiV * 4];
        }
        __syncthreads();
        #pragma unroll
        for (int pass = 0; pass < 2; ++pass) {
            const int ii = (t & 3) + pass * 4;
            *(bf16x8*)&lp[rP][ii * 8] = tp[pass];
        }
        #pragma unroll
        for (int pass = 0; pass < 2; ++pass) {
            const int n = pass * 32 + rrV * 2;
            const int col = n ^ ((iiV & 7) << 3);
            const float4 va = tv[2*pass], vb = tv[2*pass+1];
            const float a0[4] = {va.x, va.y, va.z, va.w};
            const float b0[4] = {vb.x, vb.y, vb.z, vb.w};
            #pragma unroll
            for (int c = 0; c < 4; ++c) {
                bf16x2 h = {(__bf16)a0[c], (__bf16)b0[c]};
                *(bf16x2*)&lv[iiV * 4 + c][col] = h;
            }
        }
        __syncthreads();

        const int row = lane & 15, hi = lane >> 4;
        const int key = (4 * w + (row >> 2)) & 7;
        #pragma unroll
        for (int ks = 0; ks < 2; ++ks) {
            const int col = (ks * 32 + hi * 8) ^ (key << 3);
            const bf16x8 bfrag = *(bf16x8*)&lv[w * 16 + row][col];
            #pragma unroll
            for (int am = 0; am < 4; ++am) {
                const bf16x8 afrag = *(bf16x8*)&lp[am * 16 + row][ks * 32 + hi * 8];
                acc_in[am] = mfma16(afrag, bfrag, acc_in[am]);
            }
        }
        // chunk boundary (every 4 iters = 256 tokens): rescale + flush
        if ((it & 3) == 3) {
            const int cl = it >> 2;
            #pragma unroll
            for (int am = 0; am < 4; ++am) {
                #pragma unroll
                for (int j = 0; j < 4; ++j) {
                    const float r = rsc[cl][am * 16 + hi * 4 + j];
                    acc_tot[am][j] += r * acc_in[am][j];
                    acc_in[am][j] = 0.f;
                }
            }
        }
    }

    const int col = lane & 15, hi = lane >> 4;
    #pragma unroll
    for (int am = 0; am < 4; ++am)
        #pragma unroll
        for (int j = 0; j < 4; ++j) {
            const int p = am * 16 + hi * 4 + j;
            part[(size_t)sp * (BB * PP * DD) + ((size_t)b * PP + p) * DD + d0 + w * 16 + col] = acc_tot[am][j];
        }
}

// ---------------------------------------------------------------------------
// K4: out[b,p,d] = (sum_sp part) / D[p],  D = sum_c exp(m_c - M) * l_c
// ---------------------------------------------------------------------------
__global__ __launch_bounds__(256) void k_combine(const float* __restrict__ part,
                                                 const float* __restrict__ statm,
                                                 const float* __restrict__ statl,
                                                 float* __restrict__ out) {
    const size_t idx = ((size_t)blockIdx.x * 256 + threadIdx.x);  // f32x4 units
    const size_t e = idx * 4;
    const int bp = (int)(e / DD);
    const int b = bp >> 6, p = bp & 63;

    float M = -1e30f;
    #pragma unroll
    for (int c = 0; c < 16; ++c) M = fmaxf(M, statm[((size_t)b * 16 + c) * 64 + p]);
    float D = 0.f;
    #pragma unroll
    for (int c = 0; c < 16; ++c)
        D += __expf(statm[((size_t)b * 16 + c) * 64 + p] - M) * statl[((size_t)b * 16 + c) * 64 + p];
    const float inv = 1.f / D;

    const f32x4* p4 = (const f32x4*)part;
    const size_t stride4 = (size_t)BB * PP * DD / 4;
    f32x4 v = p4[idx] + p4[stride4 + idx] + p4[2 * stride4 + idx] + p4[3 * stride4 + idx];
    ((f32x4*)out)[idx] = v * inv;
}

extern "C" void kernel_launch(void* const* d_in, const int* in_sizes, int n_in,
                              void* d_out, int out_size, void* d_ws, size_t ws_size,
                              hipStream_t stream) {
    const float* x = (const float*)d_in[0];   // [16, 4096, 768]
    const float* q = (const float*)d_in[1];   // [16, 64, 768]
    float* out = (float*)d_out;               // [16, 64, 768]

    char* ws = (char*)d_ws;
    __bf16* Pm   = (__bf16*)ws;                         // 8 MB  [16][64][4096]
    float* statm = (float*)(ws + 8388608);              // 64 KB [16][16][64]
    float* statl = (float*)(ws + 8454144);              // 64 KB
    float* part  = (float*)(ws + 8519680);              // 12.6 MB [4][16][64][768]

    hipLaunchKernelGGL(k_qk_sm,  dim3(256), dim3(512), 0, stream, x, q, Pm, statm, statl);
    hipLaunchKernelGGL(k_pv,     dim3(768), dim3(256), 0, stream, x, Pm, statm, part);
    hipLaunchKernelGGL(k_combine,dim3(768), dim3(256), 0, stream, part, statm, statl, out);
}